// Round 5
// baseline (418.198 us; speedup 1.0000x reference)
//
#include <hip/hip_runtime.h>
#include <math.h>

typedef float f4 __attribute__((ext_vector_type(4)));

namespace {
constexpr int NZ = 48, NY = 256, NX = 512;
constexpr int SY = NX;           // y stride (elements)
constexpr int SZ = NX * NY;      // z stride (elements)
constexpr int NTOT = NZ * NY * NX;
constexpr float INV_DX = 1.0f / 100000.0f;
constexpr float INV_DY = 1.0f / 100000.0f;
constexpr float INV_DZ = 1.0f / 500.0f;
}

__device__ __forceinline__ f4 sp(float s) { return (f4){s, s, s, s}; }

__device__ __forceinline__ f4 ldv(const float* __restrict__ f, int e) {
    return *reinterpret_cast<const f4*>(f + e);
}

// ---- x-axis: per-element window [L | C | R], thread covers i = x0..x0+3 ----
__device__ __forceinline__ void grad2x(f4 L, f4 C, f4 R, int x0, float inv_h,
                                       f4& g, f4& gg) {
    const float h1 = inv_h, h2 = 0.5f * inv_h;
    float win[12] = {L[0], L[1], L[2], L[3], C[0], C[1], C[2], C[3],
                     R[0], R[1], R[2], R[3]};
#pragma unroll
    for (int j = 0; j < 4; ++j) {
        g[j]  = (win[5 + j] - win[3 + j]) * h2;
        gg[j] = ((win[6 + j] - win[4 + j]) * h2 - (win[4 + j] - win[2 + j]) * h2) * h2;
    }
    if (x0 == 0) {                       // i==0 and i==1 edge formulas
        g[0]  = (C[1] - C[0]) * h1;
        gg[0] = ((C[2] - C[0]) * h2 - g[0]) * h1;
        gg[1] = ((C[3] - C[1]) * h2 - (C[1] - C[0]) * h1) * h2;
    } else if (x0 == NX - 4) {           // i==n-2 and i==n-1
        gg[2] = ((C[3] - C[2]) * h1 - (C[2] - C[0]) * h2) * h2;
        g[3]  = (C[3] - C[2]) * h1;
        gg[3] = (g[3] - (C[3] - C[1]) * h2) * h1;
    }
}

__device__ __forceinline__ f4 grad1x(f4 L, f4 C, f4 R, int x0, float inv_h) {
    const float h1 = inv_h, h2 = 0.5f * inv_h;
    f4 g;
    g[0] = (C[1] - L[3]) * h2;
    g[1] = (C[2] - C[0]) * h2;
    g[2] = (C[3] - C[1]) * h2;
    g[3] = (R[0] - C[2]) * h2;
    if (x0 == 0)            g[0] = (C[1] - C[0]) * h1;
    else if (x0 == NX - 4)  g[3] = (C[3] - C[2]) * h1;
    return g;
}

// ---- y/z axes: whole-vector stencil, index i uniform across the f4 ----
__device__ __forceinline__ void grad2v(f4 m2, f4 m1, f4 c, f4 p1, f4 p2,
                                       int i, int n, float inv_h, f4& g, f4& gg) {
    const float h1 = inv_h, h2 = 0.5f * inv_h;
    if (i >= 2 && i <= n - 3) {
        g  = (p1 - m1) * sp(h2);
        gg = ((p2 - c) * sp(h2) - (c - m2) * sp(h2)) * sp(h2);
    } else if (i == 0) {
        g  = (p1 - c) * sp(h1);
        gg = ((p2 - c) * sp(h2) - g) * sp(h1);
    } else if (i == 1) {
        g  = (p1 - m1) * sp(h2);
        gg = ((p2 - c) * sp(h2) - (c - m1) * sp(h1)) * sp(h2);
    } else if (i == n - 2) {
        g  = (p1 - m1) * sp(h2);
        gg = ((p1 - c) * sp(h1) - (c - m2) * sp(h2)) * sp(h2);
    } else { // i == n-1
        g  = (c - m1) * sp(h1);
        gg = (g - (c - m2) * sp(h2)) * sp(h1);
    }
}

__device__ __forceinline__ f4 grad1v(f4 m1, f4 c, f4 p1, int i, int n, float inv_h) {
    if (i == 0)     return (p1 - c) * sp(inv_h);
    if (i == n - 1) return (c - m1) * sp(inv_h);
    return (p1 - m1) * sp(0.5f * inv_h);
}

struct Offs {
    int xm, xp;
    int m1y, m2y, p1y, p2y;
    int m1z, m2z, p1z, p2z;
    int x0, y, z;
};

__device__ __forceinline__ Offs make_offs(int x0, int y, int z) {
    Offs o;
    o.x0 = x0; o.y = y; o.z = z;
    o.xm = (x0 > 0) ? -4 : 0;
    o.xp = (x0 < NX - 4) ? 4 : 0;
    o.m1y = (y > 0) ? -SY : 0;
    o.m2y = (y > 1) ? -2 * SY : o.m1y;
    o.p1y = (y < NY - 1) ? SY : 0;
    o.p2y = (y < NY - 2) ? 2 * SY : o.p1y;
    o.m1z = (z > 0) ? -SZ : 0;
    o.m2z = (z > 1) ? -2 * SZ : o.m1z;
    o.p1z = (z < NZ - 1) ? SZ : 0;
    o.p2z = (z < NZ - 2) ? 2 * SZ : o.p1z;
    return o;
}

__device__ __forceinline__ void field_grad2(const float* __restrict__ f, int e,
                                            const Offs& o, f4 C,
                                            f4& gx, f4& gy, f4& gz, f4& lap) {
    f4 L = ldv(f, e + o.xm);
    f4 R = ldv(f, e + o.xp);
    f4 gg;
    grad2x(L, C, R, o.x0, INV_DX, gx, gg);
    lap = gg;
    grad2v(ldv(f, e + o.m2y), ldv(f, e + o.m1y), C, ldv(f, e + o.p1y),
           ldv(f, e + o.p2y), o.y, NY, INV_DY, gy, gg);
    lap += gg;
    grad2v(ldv(f, e + o.m2z), ldv(f, e + o.m1z), C, ldv(f, e + o.p1z),
           ldv(f, e + o.p2z), o.z, NZ, INV_DZ, gz, gg);
    lap += gg;
}

__device__ __forceinline__ void field_grad1(const float* __restrict__ f, int e,
                                            const Offs& o, f4 C,
                                            f4& gx, f4& gy, f4& gz) {
    f4 L = ldv(f, e + o.xm);
    f4 R = ldv(f, e + o.xp);
    gx = grad1x(L, C, R, o.x0, INV_DX);
    gy = grad1v(ldv(f, e + o.m1y), C, ldv(f, e + o.p1y), o.y, NY, INV_DY);
    gz = grad1v(ldv(f, e + o.m1z), C, ldv(f, e + o.p1z), o.z, NZ, INV_DZ);
}

// XCD-aware mapping: each XCD owns a 32-row y-band swept z-major (r3 winner).
__device__ __forceinline__ int map_e(int bid, int tid, int& x0, int& y, int& z) {
    const int xcd = bid & 7;
    const int j = bid >> 3;                  // 0..767
    z = j >> 4;                              // 0..47
    const int yp = (xcd << 4) | (j & 15);    // y-pair 0..127
    y = (yp << 1) | (tid >> 7);              // row 0..255
    x0 = (tid & 127) << 2;
    return z * SZ + y * SY + x0;
}

// ===================== Kernel A: momentum (du, dv, dw) =====================
__global__ __launch_bounds__(256, 6)
void pe_momentum(const float* __restrict__ u, const float* __restrict__ v,
                 const float* __restrict__ w, const float* __restrict__ p,
                 const float* __restrict__ rho,
                 const float* __restrict__ F_u, const float* __restrict__ F_v,
                 const float* __restrict__ F_w,
                 const float* __restrict__ nu_p, float* __restrict__ out) {
    int x0, y, z;
    const int e = map_e(blockIdx.x, threadIdx.x, x0, y, z);
    const Offs o = make_offs(x0, y, z);

    const float snu = nu_p[0];
    const float lat = -1.57079632679f + (3.14159265359f / 255.0f) * (float)y;
    const float fc = 2.0f * 7.2921e-5f * __sinf(lat);

    const f4 uc = ldv(u, e);
    const f4 vc = ldv(v, e);
    const f4 wc = ldv(w, e);
    const f4 rhoc = ldv(rho, e);
    const f4 inv_rs = sp(1.0f) / (rhoc + sp(1e-10f));

    // pressure gradient first (frees its window early)
    const f4 pc = ldv(p, e);
    f4 gpx, gpy, gpz;
    field_grad1(p, e, o, pc, gpx, gpy, gpz);

    f4 acc_u = ldv(F_u, e) - gpx * inv_rs + sp(fc) * vc;
    f4 acc_v = ldv(F_v, e) - gpy * inv_rs - sp(fc) * uc;
    f4 acc_w = ldv(F_w, e) - gpz * inv_rs - sp(9.80665f);

    f4 gx, gy, gz, lap;
    field_grad2(u, e, o, uc, gx, gy, gz, lap);
    acc_u += sp(snu) * lap - (uc * gx + vc * gy + wc * gz);

    field_grad2(v, e, o, vc, gx, gy, gz, lap);
    acc_v += sp(snu) * lap - (uc * gx + vc * gy + wc * gz);

    field_grad2(w, e, o, wc, gx, gy, gz, lap);
    acc_w += sp(snu) * lap - (uc * gx + vc * gy + wc * gz);

    *reinterpret_cast<f4*>(out + 0 * NTOT + e) = acc_u;
    *reinterpret_cast<f4*>(out + 1 * NTOT + e) = acc_v;
    *reinterpret_cast<f4*>(out + 2 * NTOT + e) = acc_w;
}

// ================ Kernel B: thermo (dT, dq, dp, drho) ================
__global__ __launch_bounds__(256, 6)
void pe_thermo(const float* __restrict__ u, const float* __restrict__ v,
               const float* __restrict__ w, const float* __restrict__ T,
               const float* __restrict__ q, const float* __restrict__ p,
               const float* __restrict__ rho,
               const float* __restrict__ Q, const float* __restrict__ S,
               const float* __restrict__ kappa_p, float* __restrict__ out) {
    int x0, y, z;
    const int e = map_e(blockIdx.x, threadIdx.x, x0, y, z);
    const Offs o = make_offs(x0, y, z);

    const float skap = kappa_p[0];

    const f4 uc = ldv(u, e);
    const f4 vc = ldv(v, e);
    const f4 wc = ldv(w, e);
    const f4 Tc = ldv(T, e);
    const f4 pc = ldv(p, e);
    const f4 rhoc = ldv(rho, e);

    f4 gx, gy, gz, lap;

    // T: full grad2
    field_grad2(T, e, o, Tc, gx, gy, gz, lap);
    f4 acc_T = sp(skap) * lap - (uc * gx + vc * gy + wc * gz);

    // p: z-gradient only (adiabatic term)
    const f4 dp_dz = grad1v(ldv(p, e + o.m1z), pc, ldv(p, e + o.p1z),
                            z, NZ, INV_DZ);
    acc_T += sp(287.0f / 1004.0f) * Tc * wc * dp_dz / (pc + sp(1e-10f));
    acc_T += ldv(Q, e) * sp(1.0f / 1004.0f);

    // q: grad1
    const f4 qc = ldv(q, e);
    field_grad1(q, e, o, qc, gx, gy, gz);
    f4 acc_q = ldv(S, e) - (uc * gx + vc * gy + wc * gz);

    // divergence: one axis each of u, v, w
    const f4 du_dx = grad1x(ldv(u, e + o.xm), uc, ldv(u, e + o.xp), x0, INV_DX);
    const f4 dv_dy = grad1v(ldv(v, e + o.m1y), vc, ldv(v, e + o.p1y), y, NY, INV_DY);
    const f4 dw_dz = grad1v(ldv(w, e + o.m1z), wc, ldv(w, e + o.p1z), z, NZ, INV_DZ);
    const f4 div = du_dx + dv_dy + dw_dz;

    // rho: grad1
    field_grad1(rho, e, o, rhoc, gx, gy, gz);
    const f4 acc_rho = -rhoc * div - uc * gx - vc * gy - wc * gz;

    const f4 acc_p = sp(287.0f) * (rhoc * acc_T + Tc * acc_rho);

    *reinterpret_cast<f4*>(out + 3 * NTOT + e) = acc_T;
    *reinterpret_cast<f4*>(out + 4 * NTOT + e) = acc_q;
    *reinterpret_cast<f4*>(out + 5 * NTOT + e) = acc_p;
    *reinterpret_cast<f4*>(out + 6 * NTOT + e) = acc_rho;
}

extern "C" void kernel_launch(void* const* d_in, const int* in_sizes, int n_in,
                              void* d_out, int out_size, void* d_ws, size_t ws_size,
                              hipStream_t stream) {
    const float* u     = (const float*)d_in[0];
    const float* v     = (const float*)d_in[1];
    const float* w     = (const float*)d_in[2];
    const float* T     = (const float*)d_in[3];
    const float* q     = (const float*)d_in[4];
    const float* p     = (const float*)d_in[5];
    const float* rho   = (const float*)d_in[6];
    const float* F_u   = (const float*)d_in[7];
    const float* F_v   = (const float*)d_in[8];
    const float* F_w   = (const float*)d_in[9];
    const float* Q     = (const float*)d_in[10];
    const float* S     = (const float*)d_in[11];
    const float* nu    = (const float*)d_in[12];
    const float* kappa = (const float*)d_in[13];
    float* out = (float*)d_out;

    const int grid = NTOT / 4 / 256;   // 6144 blocks
    pe_momentum<<<grid, 256, 0, stream>>>(u, v, w, p, rho, F_u, F_v, F_w, nu, out);
    pe_thermo<<<grid, 256, 0, stream>>>(u, v, w, T, q, p, rho, Q, S, kappa, out);
}

// Round 6
// 189.395 us; speedup vs baseline: 2.2081x; 2.2081x over previous
//
#include <hip/hip_runtime.h>

typedef float f4 __attribute__((ext_vector_type(4)));

namespace {
constexpr int NZ = 48, NY = 256, NX = 512;
constexpr int SY = NX;            // y stride (elements)
constexpr int SZ = NX * NY;       // z stride (elements)
constexpr int NTOT = NZ * NY * NX;
constexpr int TY = 4;             // rows per block tile
constexpr int TX = 256;           // x extent per tile (64 f4)
constexpr int LW = TX / 4 + 2;    // 66 f4 per staged row (1-f4 halo each side)
constexpr int LWF = LW * 4;       // 264 floats per staged row
constexpr float INV_DX = 1.0f / 100000.0f;
constexpr float INV_DY = 1.0f / 100000.0f;
constexpr float INV_DZ = 1.0f / 500.0f;
// LDS layout (rows of LWF floats): 4 grad2 fields x 8 rows, 3 grad1 fields x 6
constexpr int LDS_U = 0 * 8 * LWF;
constexpr int LDS_V = 1 * 8 * LWF;
constexpr int LDS_W = 2 * 8 * LWF;
constexpr int LDS_T = 3 * 8 * LWF;
constexpr int LDS_P = 4 * 8 * LWF + 0 * 6 * LWF;
constexpr int LDS_R = 4 * 8 * LWF + 1 * 6 * LWF;
constexpr int LDS_Q = 4 * 8 * LWF + 2 * 6 * LWF;
constexpr int LDS_FLOATS = 4 * 8 * LWF + 3 * 6 * LWF;   // 13200 = 51.6 KB
}

__device__ __forceinline__ f4 sp(float s) { return (f4){s, s, s, s}; }

__device__ __forceinline__ f4 ldv(const float* __restrict__ f, int e) {
    return *reinterpret_cast<const f4*>(f + e);
}

__device__ __forceinline__ f4 ldsv(const float* l, int off) {
    return *reinterpret_cast<const f4*>(l + off);
}

__device__ __forceinline__ void stv_nt(float* __restrict__ f, int e, f4 val) {
    __builtin_nontemporal_store(val, reinterpret_cast<f4*>(f + e));
}

// ---- x-axis: per-element window [L | C | R]; thread covers i = x0..x0+3 ----
__device__ __forceinline__ void grad2x(f4 L, f4 C, f4 R, int x0, float inv_h,
                                       f4& g, f4& gg) {
    const float h1 = inv_h, h2 = 0.5f * inv_h;
    float win[12] = {L[0], L[1], L[2], L[3], C[0], C[1], C[2], C[3],
                     R[0], R[1], R[2], R[3]};
#pragma unroll
    for (int j = 0; j < 4; ++j) {
        g[j]  = (win[5 + j] - win[3 + j]) * h2;
        gg[j] = ((win[6 + j] - win[4 + j]) * h2 - (win[4 + j] - win[2 + j]) * h2) * h2;
    }
    if (x0 == 0) {
        g[0]  = (C[1] - C[0]) * h1;
        gg[0] = ((C[2] - C[0]) * h2 - g[0]) * h1;
        gg[1] = ((C[3] - C[1]) * h2 - (C[1] - C[0]) * h1) * h2;
    } else if (x0 == NX - 4) {
        gg[2] = ((C[3] - C[2]) * h1 - (C[2] - C[0]) * h2) * h2;
        g[3]  = (C[3] - C[2]) * h1;
        gg[3] = (g[3] - (C[3] - C[1]) * h2) * h1;
    }
}

__device__ __forceinline__ f4 grad1x(f4 L, f4 C, f4 R, int x0, float inv_h) {
    const float h1 = inv_h, h2 = 0.5f * inv_h;
    f4 g;
    g[0] = (C[1] - L[3]) * h2;
    g[1] = (C[2] - C[0]) * h2;
    g[2] = (C[3] - C[1]) * h2;
    g[3] = (R[0] - C[2]) * h2;
    if (x0 == 0)            g[0] = (C[1] - C[0]) * h1;
    else if (x0 == NX - 4)  g[3] = (C[3] - C[2]) * h1;
    return g;
}

// ---- y/z axes: whole-vector stencil, index i uniform across the f4 ----
__device__ __forceinline__ void grad2v(f4 m2, f4 m1, f4 c, f4 p1, f4 p2,
                                       int i, int n, float inv_h, f4& g, f4& gg) {
    const float h1 = inv_h, h2 = 0.5f * inv_h;
    if (i >= 2 && i <= n - 3) {
        g  = (p1 - m1) * sp(h2);
        gg = ((p2 - c) * sp(h2) - (c - m2) * sp(h2)) * sp(h2);
    } else if (i == 0) {
        g  = (p1 - c) * sp(h1);
        gg = ((p2 - c) * sp(h2) - g) * sp(h1);
    } else if (i == 1) {
        g  = (p1 - m1) * sp(h2);
        gg = ((p2 - c) * sp(h2) - (c - m1) * sp(h1)) * sp(h2);
    } else if (i == n - 2) {
        g  = (p1 - m1) * sp(h2);
        gg = ((p1 - c) * sp(h1) - (c - m2) * sp(h2)) * sp(h2);
    } else { // i == n-1
        g  = (c - m1) * sp(h1);
        gg = (g - (c - m2) * sp(h2)) * sp(h1);
    }
}

__device__ __forceinline__ f4 grad1v(f4 m1, f4 c, f4 p1, int i, int n, float inv_h) {
    if (i == 0)     return (p1 - c) * sp(inv_h);
    if (i == n - 1) return (c - m1) * sp(inv_h);
    return (p1 - m1) * sp(0.5f * inv_h);
}

// Cooperative stage of `rows` y-rows (clamped) of one field's z-plane into LDS,
// with 1-f4 x-halo each side (clamped). Coalesced f4 streams.
__device__ __forceinline__ void stage_field(const float* __restrict__ g,
                                            float* dst, int rows, int yfirst,
                                            int xf4base, int zoff) {
    const int total = rows * LW;
    for (int s = threadIdx.x; s < total; s += 256) {
        const int r = s / LW;
        const int c = s - r * LW;
        int ry = yfirst + r;
        ry = ry < 0 ? 0 : (ry > NY - 1 ? NY - 1 : ry);
        int cx = xf4base + c - 1;
        cx = cx < 0 ? 0 : (cx > NX / 4 - 1 ? NX / 4 - 1 : cx);
        *reinterpret_cast<f4*>(dst + r * LWF + c * 4) =
            *reinterpret_cast<const f4*>(g + zoff + ry * SY + cx * 4);
    }
}

__global__ __launch_bounds__(256, 3)
void pe_lds(const float* __restrict__ u, const float* __restrict__ v,
            const float* __restrict__ w, const float* __restrict__ T,
            const float* __restrict__ q, const float* __restrict__ p,
            const float* __restrict__ rho,
            const float* __restrict__ F_u, const float* __restrict__ F_v,
            const float* __restrict__ F_w, const float* __restrict__ Q,
            const float* __restrict__ S,
            const float* __restrict__ nu_p, const float* __restrict__ kappa_p,
            float* __restrict__ out) {
    __shared__ float lds[LDS_FLOATS];

    // XCD-aware map (r3 winner): xcd = bid&7 owns y-band of 32 rows, z-major.
    // Per z per XCD: 8 y-tiles x 2 x-tiles = 16 blocks.
    const int bid = blockIdx.x;
    const int xcd = bid & 7;
    const int j = bid >> 3;              // 0..767
    const int z = j >> 4;                // 0..47
    const int rem = j & 15;
    const int ytile = rem >> 1;          // 0..7
    const int xtile = rem & 1;           // 0..1
    const int y0 = (xcd << 5) + (ytile << 2);   // first center row
    const int xf4base = xtile * (TX / 4);       // 0 or 64
    const int zoff = z * SZ;

    // ---- stage center-z plane tiles ----
    stage_field(u,   lds + LDS_U, 8, y0 - 2, xf4base, zoff);
    stage_field(v,   lds + LDS_V, 8, y0 - 2, xf4base, zoff);
    stage_field(w,   lds + LDS_W, 8, y0 - 2, xf4base, zoff);
    stage_field(T,   lds + LDS_T, 8, y0 - 2, xf4base, zoff);
    stage_field(p,   lds + LDS_P, 6, y0 - 1, xf4base, zoff);
    stage_field(rho, lds + LDS_R, 6, y0 - 1, xf4base, zoff);
    stage_field(q,   lds + LDS_Q, 6, y0 - 1, xf4base, zoff);
    __syncthreads();

    // ---- per-thread point: row r (0..3), f4 column xl (0..63) ----
    const int r = threadIdx.x >> 6;
    const int xl = threadIdx.x & 63;
    const int y = y0 + r;
    const int x0 = xtile * TX + (xl << 2);      // global x of elem 0
    const int e = zoff + y * SY + x0;
    const int cb = (xl + 1) << 2;               // float col of center f4 in LDS

    // z-halo offsets (clamped; clamped values unused by edge formulas)
    const int m1z = (z > 0) ? -SZ : 0;
    const int m2z = (z > 1) ? -2 * SZ : m1z;
    const int p1z = (z < NZ - 1) ? SZ : 0;
    const int p2z = (z < NZ - 2) ? 2 * SZ : p1z;

    const float snu = nu_p[0];
    const float skap = kappa_p[0];
    const float lat = -1.57079632679f + (3.14159265359f / 255.0f) * (float)y;
    const float fc = 2.0f * 7.2921e-5f * __sinf(lat);

    // centers from LDS
    const float* Bu = lds + LDS_U + (r + 2) * LWF + cb;
    const float* Bv = lds + LDS_V + (r + 2) * LWF + cb;
    const float* Bw = lds + LDS_W + (r + 2) * LWF + cb;
    const float* Bt = lds + LDS_T + (r + 2) * LWF + cb;
    const float* Bp = lds + LDS_P + (r + 1) * LWF + cb;
    const float* Br = lds + LDS_R + (r + 1) * LWF + cb;
    const float* Bq = lds + LDS_Q + (r + 1) * LWF + cb;

    const f4 uc = ldsv(Bu, 0);
    const f4 vc = ldsv(Bv, 0);
    const f4 wc = ldsv(Bw, 0);
    const f4 Tc = ldsv(Bt, 0);
    const f4 pc = ldsv(Bp, 0);
    const f4 rhoc = ldsv(Br, 0);
    const f4 qc = ldsv(Bq, 0);

    f4 gx, gy, gz, ggx, ggy, ggz, lap;

    // ---- u ----
    grad2x(ldsv(Bu, -4), uc, ldsv(Bu, 4), x0, INV_DX, gx, ggx);
    grad2v(ldsv(Bu, -2 * LWF), ldsv(Bu, -LWF), uc, ldsv(Bu, LWF), ldsv(Bu, 2 * LWF),
           y, NY, INV_DY, gy, ggy);
    grad2v(ldv(u, e + m2z), ldv(u, e + m1z), uc, ldv(u, e + p1z), ldv(u, e + p2z),
           z, NZ, INV_DZ, gz, ggz);
    lap = ggx + ggy + ggz;
    const f4 du_dx = gx;
    f4 acc_u = sp(snu) * lap - (uc * gx + vc * gy + wc * gz);

    // ---- v ----
    grad2x(ldsv(Bv, -4), vc, ldsv(Bv, 4), x0, INV_DX, gx, ggx);
    grad2v(ldsv(Bv, -2 * LWF), ldsv(Bv, -LWF), vc, ldsv(Bv, LWF), ldsv(Bv, 2 * LWF),
           y, NY, INV_DY, gy, ggy);
    grad2v(ldv(v, e + m2z), ldv(v, e + m1z), vc, ldv(v, e + p1z), ldv(v, e + p2z),
           z, NZ, INV_DZ, gz, ggz);
    lap = ggx + ggy + ggz;
    const f4 dv_dy = gy;
    f4 acc_v = sp(snu) * lap - (uc * gx + vc * gy + wc * gz);

    // ---- w ----
    grad2x(ldsv(Bw, -4), wc, ldsv(Bw, 4), x0, INV_DX, gx, ggx);
    grad2v(ldsv(Bw, -2 * LWF), ldsv(Bw, -LWF), wc, ldsv(Bw, LWF), ldsv(Bw, 2 * LWF),
           y, NY, INV_DY, gy, ggy);
    grad2v(ldv(w, e + m2z), ldv(w, e + m1z), wc, ldv(w, e + p1z), ldv(w, e + p2z),
           z, NZ, INV_DZ, gz, ggz);
    lap = ggx + ggy + ggz;
    const f4 dw_dz = gz;
    f4 acc_w = sp(snu) * lap - (uc * gx + vc * gy + wc * gz);

    const f4 div = du_dx + dv_dy + dw_dz;

    // ---- T ----
    grad2x(ldsv(Bt, -4), Tc, ldsv(Bt, 4), x0, INV_DX, gx, ggx);
    grad2v(ldsv(Bt, -2 * LWF), ldsv(Bt, -LWF), Tc, ldsv(Bt, LWF), ldsv(Bt, 2 * LWF),
           y, NY, INV_DY, gy, ggy);
    grad2v(ldv(T, e + m2z), ldv(T, e + m1z), Tc, ldv(T, e + p1z), ldv(T, e + p2z),
           z, NZ, INV_DZ, gz, ggz);
    lap = ggx + ggy + ggz;
    f4 acc_T = sp(skap) * lap - (uc * gx + vc * gy + wc * gz);

    // ---- rho (grad1) ----
    gx = grad1x(ldsv(Br, -4), rhoc, ldsv(Br, 4), x0, INV_DX);
    gy = grad1v(ldsv(Br, -LWF), rhoc, ldsv(Br, LWF), y, NY, INV_DY);
    gz = grad1v(ldv(rho, e + m1z), rhoc, ldv(rho, e + p1z), z, NZ, INV_DZ);
    const f4 acc_rho = -rhoc * div - uc * gx - vc * gy - wc * gz;

    // ---- p (grad1) ----
    gx = grad1x(ldsv(Bp, -4), pc, ldsv(Bp, 4), x0, INV_DX);
    gy = grad1v(ldsv(Bp, -LWF), pc, ldsv(Bp, LWF), y, NY, INV_DY);
    gz = grad1v(ldv(p, e + m1z), pc, ldv(p, e + p1z), z, NZ, INV_DZ);
    const f4 inv_rs = sp(1.0f) / (rhoc + sp(1e-10f));
    acc_u -= gx * inv_rs;
    acc_v -= gy * inv_rs;
    acc_w -= gz * inv_rs;
    acc_T += sp(287.0f / 1004.0f) * Tc * wc * gz / (pc + sp(1e-10f));

    // ---- q (grad1) ----
    gx = grad1x(ldsv(Bq, -4), qc, ldsv(Bq, 4), x0, INV_DX);
    gy = grad1v(ldsv(Bq, -LWF), qc, ldsv(Bq, LWF), y, NY, INV_DY);
    gz = grad1v(ldv(q, e + m1z), qc, ldv(q, e + p1z), z, NZ, INV_DZ);
    f4 acc_q = -(uc * gx + vc * gy + wc * gz);

    // ---- forcings / Coriolis / sources ----
    acc_u += sp(fc) * vc + ldv(F_u, e);
    acc_v += ldv(F_v, e) - sp(fc) * uc;
    acc_w += ldv(F_w, e) - sp(9.80665f);
    acc_T += ldv(Q, e) * sp(1.0f / 1004.0f);
    acc_q += ldv(S, e);

    const f4 acc_p = sp(287.0f) * (rhoc * acc_T + Tc * acc_rho);

    stv_nt(out, 0 * NTOT + e, acc_u);
    stv_nt(out, 1 * NTOT + e, acc_v);
    stv_nt(out, 2 * NTOT + e, acc_w);
    stv_nt(out, 3 * NTOT + e, acc_T);
    stv_nt(out, 4 * NTOT + e, acc_q);
    stv_nt(out, 5 * NTOT + e, acc_p);
    stv_nt(out, 6 * NTOT + e, acc_rho);
}

extern "C" void kernel_launch(void* const* d_in, const int* in_sizes, int n_in,
                              void* d_out, int out_size, void* d_ws, size_t ws_size,
                              hipStream_t stream) {
    const float* u     = (const float*)d_in[0];
    const float* v     = (const float*)d_in[1];
    const float* w     = (const float*)d_in[2];
    const float* T     = (const float*)d_in[3];
    const float* q     = (const float*)d_in[4];
    const float* p     = (const float*)d_in[5];
    const float* rho   = (const float*)d_in[6];
    const float* F_u   = (const float*)d_in[7];
    const float* F_v   = (const float*)d_in[8];
    const float* F_w   = (const float*)d_in[9];
    const float* Q     = (const float*)d_in[10];
    const float* S     = (const float*)d_in[11];
    const float* nu    = (const float*)d_in[12];
    const float* kappa = (const float*)d_in[13];
    float* out = (float*)d_out;

    // 2 x-tiles * 64 y-tiles * 48 z = 6144 blocks
    pe_lds<<<6144, 256, 0, stream>>>(u, v, w, T, q, p, rho,
                                     F_u, F_v, F_w, Q, S, nu, kappa, out);
}